// Round 1
// baseline (496.586 us; speedup 1.0000x reference)
//
#include <hip/hip_runtime.h>

// Involution b=8, c=64, h=w=128, K=3, G=8, r=2.
// kern = Wc @ x_center + bb, Wc = w_span@w_reduce (72x64), bb = w_span@b_reduce + b_span.
// R8 vs R7: 2 pixels (horizontal pair) per thread, float2 loads/stores.
//   - Phase A: one aligned float2 per channel feeds BOTH pixels' kg chains
//     (load+addr instrs per pixel halved, FMA:load ratio doubled).
//   - Phase B: per channel/row: aligned float2 at col w0 (shared cols) + two
//     clamped scalar edge loads = 9 load instrs per channel for 2 pixels
//     (was 18). Borders via clamp-offset + zeroed taps (all addrs in-bounds).
//   - float2 stores. Grid 1024 blocks; XCD bijective swizzle kept:
//     128 logical ids per XCD = one full image per XCD = 4 MiB = its L2.

#define HW 16384   // 128*128
#define WPX 128

// ws layout: [0,72) bb ;  [72 + q*1152 + c*18 + o') Wq[q][c][o']
__global__ void invol_setup(const float* __restrict__ w_reduce,
                            const float* __restrict__ b_reduce,
                            const float* __restrict__ w_span,
                            const float* __restrict__ b_span,
                            float* __restrict__ ws)
{
    const int tid = blockIdx.x * 256 + threadIdx.x;   // 0..4607
    if (tid >= 72 * 64) return;
    const int row = tid >> 6;     // 0..71
    const int c   = tid & 63;
    float s = 0.f;
#pragma unroll
    for (int i = 0; i < 32; ++i)
        s = fmaf(w_span[row * 32 + i], w_reduce[i * 64 + c], s);
    ws[72 + (row / 18) * 1152 + c * 18 + (row % 18)] = s;
    if (c == 0) {
        float t = b_span[row];
#pragma unroll
        for (int i = 0; i < 32; ++i)
            t = fmaf(w_span[row * 32 + i], b_reduce[i], t);
        ws[row] = t;
    }
}

__global__ __launch_bounds__(256, 4) void invol_main(
    const float* __restrict__ x,
    const float* __restrict__ ws,
    float* __restrict__ out)
{
    // XCD-aware bijective swizzle: nwg = 1024, 8 XCDs, 128 logical ids/XCD.
    const int bid     = blockIdx.x;
    const int logical = (bid & 7) * 128 + (bid >> 3);
    const int q  = logical & 3;             // quarter — SCALAR (SGPR)
    const int pb = logical >> 2;            // pair-block (256 pixel-pairs)

    const int P2  = pb * 256 + threadIdx.x; // global pixel-pair id, 0..65535
    const int b   = P2 >> 13;               // 8192 pairs per image
    const int hw0 = (P2 & 8191) << 1;       // even pixel index in image
    const int h   = hw0 >> 7;
    const int w0  = hw0 & 127;              // even, 0..126

    const size_t imgoff = (size_t)b * 64 * HW;
    const float* xb  = x + imgoff + hw0;
    const float* Wq  = ws + 72 + q * 1152;  // [c][18], scalar base
    const float* bbq = ws + q * 18;

    // ---- phase A: 8-wide float2 load clusters + dual FMA chains ----
    float kg0[18], kg1[18];
#pragma unroll
    for (int o = 0; o < 18; ++o) { const float t = bbq[o]; kg0[o] = t; kg1[o] = t; }

#pragma unroll
    for (int c0 = 0; c0 < 64; c0 += 8) {
        float2 xv[8];
#pragma unroll
        for (int j = 0; j < 8; ++j)
            xv[j] = *reinterpret_cast<const float2*>(xb + (size_t)(c0 + j) * HW);
#pragma unroll
        for (int j = 0; j < 8; ++j) {
#pragma unroll
            for (int o = 0; o < 18; ++o) {
                const float wv = Wq[(c0 + j) * 18 + o];
                kg0[o] = fmaf(wv, xv[j].x, kg0[o]);
                kg1[o] = fmaf(wv, xv[j].y, kg1[o]);
            }
        }
    }

    // ---- phase B prep: row-clamped offsets, masks folded into taps ----
    // tap index k = (dh+1)*3 + (dw+1); kg[0..9) = group 2q, kg[9..18) = group 2q+1
    int rof[3];
#pragma unroll
    for (int t = 0; t < 3; ++t) {
        const int hh = h + t - 1;
        const int hc = hh < 0 ? 0 : (hh > 127 ? 127 : hh);
        rof[t] = (hc - h) * WPX;
        const float m = ((unsigned)hh < 128u) ? 1.f : 0.f;
#pragma unroll
        for (int d = 0; d < 3; ++d) {
            kg0[t * 3 + d]     *= m;  kg1[t * 3 + d]     *= m;
            kg0[9 + t * 3 + d] *= m;  kg1[9 + t * 3 + d] *= m;
        }
    }
    // column edges: pixel0 (w=w0) loses dw=-1 taps only at w0==0;
    // pixel1 (w=w0+1) loses dw=+1 taps only at w0==126. Scalar edge loads
    // are clamped in-bounds; the garbage value is multiplied by a zero tap.
    const int dwl = (w0 == 0)   ? 0 : -1;   // col of left scalar load rel. w0
    const int dwr = (w0 == 126) ? 1 : 2;    // col of right scalar load rel. w0
    if (w0 == 0) {
        kg0[0] = 0.f; kg0[3] = 0.f; kg0[6] = 0.f;
        kg0[9] = 0.f; kg0[12] = 0.f; kg0[15] = 0.f;
    }
    if (w0 == 126) {
        kg1[2] = 0.f; kg1[5] = 0.f; kg1[8] = 0.f;
        kg1[11] = 0.f; kg1[14] = 0.f; kg1[17] = 0.f;
    }

    // ---- phase B: 16 channels; per channel 3x{float2 + 2 scalar} loads,
    //      18 FMA covering both pixels, one float2 store ----
#pragma unroll
    for (int ci = 0; ci < 16; ++ci) {
        const int c = q * 16 + ci;
        const float* xc = xb + (size_t)c * HW;
        float2 vC[3];
        float  vL[3], vR[3];
#pragma unroll
        for (int t = 0; t < 3; ++t) {
            vC[t] = *reinterpret_cast<const float2*>(xc + rof[t]); // cols w0,w0+1 (8B-aligned)
            vL[t] = xc[rof[t] + dwl];                              // col w0-1 (clamped)
            vR[t] = xc[rof[t] + dwr];                              // col w0+2 (clamped)
        }
        const int kb = (ci >> 3) * 9;   // 0 or 9 — static per unrolled iter
        float acc0 = 0.f, acc1 = 0.f;
#pragma unroll
        for (int t = 0; t < 3; ++t) {
            acc0 = fmaf(kg0[kb + t * 3 + 0], vL[t],   acc0);
            acc0 = fmaf(kg0[kb + t * 3 + 1], vC[t].x, acc0);
            acc0 = fmaf(kg0[kb + t * 3 + 2], vC[t].y, acc0);
            acc1 = fmaf(kg1[kb + t * 3 + 0], vC[t].x, acc1);
            acc1 = fmaf(kg1[kb + t * 3 + 1], vC[t].y, acc1);
            acc1 = fmaf(kg1[kb + t * 3 + 2], vR[t],   acc1);
        }
        *reinterpret_cast<float2*>(out + imgoff + (size_t)c * HW + hw0) =
            make_float2(acc0, acc1);
    }
}

// fallback (round-1 kernel) if ws is too small for the weight scratch
__global__ __launch_bounds__(256) void invol_fused_fallback(
    const float* __restrict__ x,
    const float* __restrict__ w_reduce,
    const float* __restrict__ b_reduce,
    const float* __restrict__ w_span,
    const float* __restrict__ b_span,
    float* __restrict__ out)
{
    const int pid = blockIdx.x * 256 + threadIdx.x;
    const int b  = pid >> 14;
    const int hw = pid & 16383;
    const int h  = hw >> 7;
    const int w  = hw & 127;
    const float* xb   = x   + (size_t)b * 64 * HW + hw;
    float*       outb = out + (size_t)b * 64 * HW + hw;
    float y[32];
#pragma unroll
    for (int o = 0; o < 32; ++o) y[o] = b_reduce[o];
#pragma unroll 4
    for (int c = 0; c < 64; ++c) {
        const float xc = xb[(size_t)c * HW];
#pragma unroll
        for (int o = 0; o < 32; ++o)
            y[o] = fmaf(w_reduce[o * 64 + c], xc, y[o]);
    }
    for (int g = 0; g < 8; ++g) {
        float kg[9];
#pragma unroll
        for (int k = 0; k < 9; ++k) {
            float s = b_span[g * 9 + k];
#pragma unroll
            for (int i = 0; i < 32; ++i)
                s = fmaf(w_span[(g * 9 + k) * 32 + i], y[i], s);
            kg[k] = s;
        }
#pragma unroll
        for (int ci = 0; ci < 8; ++ci) {
            const int c = g * 8 + ci;
            const float* xc = xb + (size_t)c * HW;
            float acc = 0.f;
#pragma unroll
            for (int k = 0; k < 9; ++k) {
                const int dh = k / 3 - 1, dw = k % 3 - 1;
                const int hh = h + dh, ww = w + dw;
                float v = ((unsigned)hh < 128u && (unsigned)ww < 128u)
                          ? xc[dh * WPX + dw] : 0.f;
                acc = fmaf(kg[k], v, acc);
            }
            outb[(size_t)c * HW] = acc;
        }
    }
}

extern "C" void kernel_launch(void* const* d_in, const int* in_sizes, int n_in,
                              void* d_out, int out_size, void* d_ws, size_t ws_size,
                              hipStream_t stream) {
    const float* x        = (const float*)d_in[0];
    const float* w_reduce = (const float*)d_in[1];
    const float* b_reduce = (const float*)d_in[2];
    const float* w_span   = (const float*)d_in[3];
    const float* b_span   = (const float*)d_in[4];
    float* out = (float*)d_out;

    const size_t ws_needed = (size_t)(72 + 4 * 64 * 18) * sizeof(float);  // 18720 B
    if (ws_size >= ws_needed) {
        float* ws = (float*)d_ws;
        invol_setup<<<18, 256, 0, stream>>>(w_reduce, b_reduce, w_span, b_span, ws);
        const int npairs = 8 * 128 * 128 / 2;          // 65536
        invol_main<<<npairs / 256 * 4, 256, 0, stream>>>(x, ws, out);  // 1024 blocks
    } else {
        const int npix = 8 * 128 * 128;
        invol_fused_fallback<<<npix / 256, 256, 0, stream>>>(
            x, w_reduce, b_reduce, w_span, b_span, out);
    }
}

// Round 2
// 52.325 us; speedup vs baseline: 9.4904x; 9.4904x over previous
//
#include <hip/hip_runtime.h>

// Involution b=8, c=64, h=w=128, K=3, G=8, r=2.
// kern = Wc @ x_center + bb, Wc = w_span@w_reduce (72x64), bb = w_span@b_reduce + b_span.
// R9 = R7 structure (1 px/thread, 2048 blocks, XCD swizzle, proven 45.4us)
//      + Phase A packed FMA: 18 accumulators as 9 float2 pairs, weights read
//      as 8B-aligned SGPR pairs, v_pk_fma_f32 via inline asm.
//      Per channel: 1 broadcast mov + 9 pk_fma (10 VALU) vs 18 scalar FMA.
// R8 post-mortem: 2px/thread doubled the unrolled body -> partial unroll ->
//      runtime-indexed arrays demoted to scratch (WRITE 246MB vs 32MB out).
//      Keep bodies SMALL and indices static.

#define HW 16384   // 128*128
#define WPX 128

// kg element o (0..17) lives in kg2[o>>1].{x,y} — static-index lvalue access
#define KG(o) ((o) & 1 ? kg2[(o) >> 1].y : kg2[(o) >> 1].x)

// ws layout: [0,72) bb ;  [72 + q*1152 + c*18 + o') Wq[q][c][o']
__global__ void invol_setup(const float* __restrict__ w_reduce,
                            const float* __restrict__ b_reduce,
                            const float* __restrict__ w_span,
                            const float* __restrict__ b_span,
                            float* __restrict__ ws)
{
    const int tid = blockIdx.x * 256 + threadIdx.x;   // 0..4607
    if (tid >= 72 * 64) return;
    const int row = tid >> 6;     // 0..71
    const int c   = tid & 63;
    float s = 0.f;
#pragma unroll
    for (int i = 0; i < 32; ++i)
        s = fmaf(w_span[row * 32 + i], w_reduce[i * 64 + c], s);
    ws[72 + (row / 18) * 1152 + c * 18 + (row % 18)] = s;
    if (c == 0) {
        float t = b_span[row];
#pragma unroll
        for (int i = 0; i < 32; ++i)
            t = fmaf(w_span[row * 32 + i], b_reduce[i], t);
        ws[row] = t;
    }
}

__global__ __launch_bounds__(256, 4) void invol_main(
    const float* __restrict__ x,
    const float* __restrict__ ws,
    float* __restrict__ out)
{
    // XCD-aware swizzle: nwg = 2048, 8 XCDs, 256 logical ids per XCD.
    const int bid     = blockIdx.x;
    const int logical = (bid & 7) * 256 + (bid >> 3);
    const int q  = logical & 3;             // quarter — SCALAR (SGPR)
    const int pb = logical >> 2;            // pixel block (256 pixels)

    const int P  = pb * 256 + threadIdx.x;  // global pixel
    const int b  = P >> 14;
    const int hw = P & 16383;
    const int h  = hw >> 7;
    const int w  = hw & 127;

    const size_t imgoff = (size_t)b * 64 * HW;
    const float* xb  = x + imgoff + hw;
    const float* Wq  = ws + 72 + q * 1152;  // [c][18], scalar base, rows 8B-aligned
    const float* bbq = ws + q * 18;         // 8B-aligned (18 even)

    // ---- phase A: 8-wide load clusters + packed FMA pairs ----
    float2 kg2[9];
#pragma unroll
    for (int i = 0; i < 9; ++i)
        kg2[i] = *reinterpret_cast<const float2*>(bbq + 2 * i);

#pragma unroll
    for (int c0 = 0; c0 < 64; c0 += 8) {
        float xv[8];
#pragma unroll
        for (int j = 0; j < 8; ++j)
            xv[j] = xb[(size_t)(c0 + j) * HW];
#pragma unroll
        for (int j = 0; j < 8; ++j) {
            const float2 xx = make_float2(xv[j], xv[j]);   // broadcast (1 mov)
#pragma unroll
            for (int i = 0; i < 9; ++i) {
                // wave-uniform weight pair -> SGPR pair (VOP3P src0 may be SGPR)
                const float2 wp =
                    *reinterpret_cast<const float2*>(Wq + (c0 + j) * 18 + 2 * i);
                asm("v_pk_fma_f32 %0, %1, %2, %0"
                    : "+v"(kg2[i]) : "s"(wp), "v"(xx));
            }
        }
    }

    // ---- phase B prep: clamped offsets, masks folded into taps (R7) ----
    int off[9];
#pragma unroll
    for (int k = 0; k < 9; ++k) {
        const int dh = k / 3 - 1, dw = k % 3 - 1;
        const int hh = h + dh, ww = w + dw;
        const bool inb = ((unsigned)hh < 128u) && ((unsigned)ww < 128u);
        const int hc = hh < 0 ? 0 : (hh > 127 ? 127 : hh);
        const int wc = ww < 0 ? 0 : (ww > 127 ? 127 : ww);
        off[k] = (hc - h) * WPX + (wc - w);
        const float m = inb ? 1.f : 0.f;
        KG(k)     *= m;
        KG(9 + k) *= m;
    }

    // ---- phase B: 16 channels (groups 2q, 2q+1), 9 loads + 9 FMA each (R7) ----
#pragma unroll
    for (int ci = 0; ci < 16; ++ci) {
        const int c = q * 16 + ci;
        const float* xc = xb + (size_t)c * HW;
        float v[9];
#pragma unroll
        for (int k = 0; k < 9; ++k)
            v[k] = xc[off[k]];
        const int kb = (ci >> 3) * 9;   // 0 or 9 — static per unrolled iter
        float acc = 0.f;
#pragma unroll
        for (int k = 0; k < 9; ++k)
            acc = fmaf(KG(kb + k), v[k], acc);
        out[imgoff + (size_t)c * HW + hw] = acc;
    }
}

// fallback (round-1 kernel) if ws is too small for the weight scratch
__global__ __launch_bounds__(256) void invol_fused_fallback(
    const float* __restrict__ x,
    const float* __restrict__ w_reduce,
    const float* __restrict__ b_reduce,
    const float* __restrict__ w_span,
    const float* __restrict__ b_span,
    float* __restrict__ out)
{
    const int pid = blockIdx.x * 256 + threadIdx.x;
    const int b  = pid >> 14;
    const int hw = pid & 16383;
    const int h  = hw >> 7;
    const int w  = hw & 127;
    const float* xb   = x   + (size_t)b * 64 * HW + hw;
    float*       outb = out + (size_t)b * 64 * HW + hw;
    float y[32];
#pragma unroll
    for (int o = 0; o < 32; ++o) y[o] = b_reduce[o];
#pragma unroll 4
    for (int c = 0; c < 64; ++c) {
        const float xc = xb[(size_t)c * HW];
#pragma unroll
        for (int o = 0; o < 32; ++o)
            y[o] = fmaf(w_reduce[o * 64 + c], xc, y[o]);
    }
    for (int g = 0; g < 8; ++g) {
        float kg[9];
#pragma unroll
        for (int k = 0; k < 9; ++k) {
            float s = b_span[g * 9 + k];
#pragma unroll
            for (int i = 0; i < 32; ++i)
                s = fmaf(w_span[(g * 9 + k) * 32 + i], y[i], s);
            kg[k] = s;
        }
#pragma unroll
        for (int ci = 0; ci < 8; ++ci) {
            const int c = g * 8 + ci;
            const float* xc = xb + (size_t)c * HW;
            float acc = 0.f;
#pragma unroll
            for (int k = 0; k < 9; ++k) {
                const int dh = k / 3 - 1, dw = k % 3 - 1;
                const int hh = h + dh, ww = w + dw;
                float v = ((unsigned)hh < 128u && (unsigned)ww < 128u)
                          ? xc[dh * WPX + dw] : 0.f;
                acc = fmaf(kg[k], v, acc);
            }
            outb[(size_t)c * HW] = acc;
        }
    }
}

extern "C" void kernel_launch(void* const* d_in, const int* in_sizes, int n_in,
                              void* d_out, int out_size, void* d_ws, size_t ws_size,
                              hipStream_t stream) {
    const float* x        = (const float*)d_in[0];
    const float* w_reduce = (const float*)d_in[1];
    const float* b_reduce = (const float*)d_in[2];
    const float* w_span   = (const float*)d_in[3];
    const float* b_span   = (const float*)d_in[4];
    float* out = (float*)d_out;

    const size_t ws_needed = (size_t)(72 + 4 * 64 * 18) * sizeof(float);  // 18720 B
    if (ws_size >= ws_needed) {
        float* ws = (float*)d_ws;
        invol_setup<<<18, 256, 0, stream>>>(w_reduce, b_reduce, w_span, b_span, ws);
        const int npix = 8 * 128 * 128;               // 131072
        invol_main<<<npix / 256 * 4, 256, 0, stream>>>(x, ws, out);
    } else {
        const int npix = 8 * 128 * 128;
        invol_fused_fallback<<<npix / 256, 256, 0, stream>>>(
            x, w_reduce, b_reduce, w_span, b_span, out);
    }
}

// Round 3
// 46.759 us; speedup vs baseline: 10.6202x; 1.1191x over previous
//
#include <hip/hip_runtime.h>

// Involution b=8, c=64, h=w=128, K=3, G=8, r=2.
// kern = Wc @ x_center + bb, Wc = w_span@w_reduce (72x64), bb = w_span@b_reduce + b_span.
// R10 = R7 structure (1 px/thread, 2048 blocks, XCD swizzle) + Phase B via LDS:
//   - Stage 16ch x 4 rows (h0-1..h0+2, contiguous 2KB/ch in global) into 32KB
//     LDS tile: 8 coalesced float4 loads + 8 ds_write_b128 per thread.
//   - Phase B taps become ds_read_b32 (9 addr VGPRs reused, per-channel imm).
//     vmem instr/thread: 208 -> 88; the 144 tap reads move to the DS pipe.
//   - Borders: clamp tap address into staged rows (real data, finite) and
//     zero the tap weight — proven R7 scheme, no NaN*0 hazard.
// R9 post-mortem: pk_fma cut VALUBusy 42->26% but dur rose -> NOT VALU-bound;
//     memory-pipe bound. R8 post-mortem: keep unrolled bodies small, indices static.

#define HW 16384   // 128*128
#define WPX 128

// ws layout: [0,72) bb ;  [72 + q*1152 + c*18 + o') Wq[q][c][o']
__global__ void invol_setup(const float* __restrict__ w_reduce,
                            const float* __restrict__ b_reduce,
                            const float* __restrict__ w_span,
                            const float* __restrict__ b_span,
                            float* __restrict__ ws)
{
    const int tid = blockIdx.x * 256 + threadIdx.x;   // 0..4607
    if (tid >= 72 * 64) return;
    const int row = tid >> 6;     // 0..71
    const int c   = tid & 63;
    float s = 0.f;
#pragma unroll
    for (int i = 0; i < 32; ++i)
        s = fmaf(w_span[row * 32 + i], w_reduce[i * 64 + c], s);
    ws[72 + (row / 18) * 1152 + c * 18 + (row % 18)] = s;
    if (c == 0) {
        float t = b_span[row];
#pragma unroll
        for (int i = 0; i < 32; ++i)
            t = fmaf(w_span[row * 32 + i], b_reduce[i], t);
        ws[row] = t;
    }
}

__global__ __launch_bounds__(256, 4) void invol_main(
    const float* __restrict__ x,
    const float* __restrict__ ws,
    float* __restrict__ out)
{
    // XCD-aware swizzle: nwg = 2048, 8 XCDs, 256 logical ids per XCD.
    const int bid     = blockIdx.x;
    const int logical = (bid & 7) * 256 + (bid >> 3);
    const int q  = logical & 3;             // quarter — SCALAR (SGPR)
    const int pb = logical >> 2;            // pixel block (256 pixels = 2 rows)

    const int P  = pb * 256 + threadIdx.x;  // global pixel
    const int b  = P >> 14;                 // block-uniform (64 blocks/image)
    const int hw = P & 16383;
    const int h  = hw >> 7;
    const int w  = hw & 127;

    const size_t imgoff = (size_t)b * 64 * HW;
    const float* xb  = x + imgoff + hw;
    const float* Wq  = ws + 72 + q * 1152;  // [c][18], scalar base
    const float* bbq = ws + q * 18;

    // ---- staging: 16 channels x 4 rows (start..start+3) -> 32 KB LDS ----
    // start clamped so the staged window always contains every clamped tap row.
    __shared__ __align__(16) float tile[16 * 4 * WPX];   // [ch][row][col]
    const int h0    = ((pb * 256) & 16383) >> 7;         // block's first row
    const int start = h0 - 1 < 0 ? 0 : (h0 - 1 > 124 ? 124 : h0 - 1);
#pragma unroll
    for (int i = 0; i < 8; ++i) {
        const int f  = threadIdx.x + 256 * i;   // float4 id, 0..2047
        const int cl = f >> 7;                  // local channel 0..15
        const int o  = f & 127;                 // float4 within 2KB channel tile
        const float4 v = reinterpret_cast<const float4*>(
            x + imgoff + (size_t)(q * 16 + cl) * HW + start * WPX)[o];
        reinterpret_cast<float4*>(tile)[f] = v;
    }

    // ---- phase A: 8-wide load clusters + FMA (R7 verbatim) ----
    float kg[18];
#pragma unroll
    for (int o = 0; o < 18; ++o) kg[o] = bbq[o];

#pragma unroll
    for (int c0 = 0; c0 < 64; c0 += 8) {
        float xv[8];
#pragma unroll
        for (int j = 0; j < 8; ++j)
            xv[j] = xb[(size_t)(c0 + j) * HW];
#pragma unroll
        for (int j = 0; j < 8; ++j) {
#pragma unroll
            for (int o = 0; o < 18; ++o)
                kg[o] = fmaf(Wq[(c0 + j) * 18 + o], xv[j], kg[o]);
        }
    }

    // ---- phase B prep: LDS byte offsets, masks folded into taps ----
    int vofs[9];
#pragma unroll
    for (int k = 0; k < 9; ++k) {
        const int dh = k / 3 - 1, dw = k % 3 - 1;
        const int hh = h + dh, ww = w + dw;
        const bool inb = ((unsigned)hh < 128u) && ((unsigned)ww < 128u);
        const int hc = hh < 0 ? 0 : (hh > 127 ? 127 : hh);   // in [start, start+3]
        const int wc = ww < 0 ? 0 : (ww > 127 ? 127 : ww);
        vofs[k] = ((hc - start) * WPX + wc) * 4;             // byte offset in tile row-space
        const float m = inb ? 1.f : 0.f;
        kg[k]     *= m;
        kg[9 + k] *= m;
    }

    __syncthreads();

    // ---- phase B: 16 channels; 9 ds_read_b32 + 9 FMA + 1 store each ----
    const char* tbytes = reinterpret_cast<const char*>(tile);
#pragma unroll
    for (int ci = 0; ci < 16; ++ci) {
        const int c = q * 16 + ci;
        float v[9];
#pragma unroll
        for (int k = 0; k < 9; ++k)
            v[k] = *reinterpret_cast<const float*>(tbytes + ci * 2048 + vofs[k]);
        const int kb = (ci >> 3) * 9;   // 0 or 9 — static per unrolled iter
        float acc = 0.f;
#pragma unroll
        for (int k = 0; k < 9; ++k)
            acc = fmaf(kg[kb + k], v[k], acc);
        out[imgoff + (size_t)c * HW + hw] = acc;
    }
}

// fallback (round-1 kernel) if ws is too small for the weight scratch
__global__ __launch_bounds__(256) void invol_fused_fallback(
    const float* __restrict__ x,
    const float* __restrict__ w_reduce,
    const float* __restrict__ b_reduce,
    const float* __restrict__ w_span,
    const float* __restrict__ b_span,
    float* __restrict__ out)
{
    const int pid = blockIdx.x * 256 + threadIdx.x;
    const int b  = pid >> 14;
    const int hw = pid & 16383;
    const int h  = hw >> 7;
    const int w  = hw & 127;
    const float* xb   = x   + (size_t)b * 64 * HW + hw;
    float*       outb = out + (size_t)b * 64 * HW + hw;
    float y[32];
#pragma unroll
    for (int o = 0; o < 32; ++o) y[o] = b_reduce[o];
#pragma unroll 4
    for (int c = 0; c < 64; ++c) {
        const float xc = xb[(size_t)c * HW];
#pragma unroll
        for (int o = 0; o < 32; ++o)
            y[o] = fmaf(w_reduce[o * 64 + c], xc, y[o]);
    }
    for (int g = 0; g < 8; ++g) {
        float kg[9];
#pragma unroll
        for (int k = 0; k < 9; ++k) {
            float s = b_span[g * 9 + k];
#pragma unroll
            for (int i = 0; i < 32; ++i)
                s = fmaf(w_span[(g * 9 + k) * 32 + i], y[i], s);
            kg[k] = s;
        }
#pragma unroll
        for (int ci = 0; ci < 8; ++ci) {
            const int c = g * 8 + ci;
            const float* xc = xb + (size_t)c * HW;
            float acc = 0.f;
#pragma unroll
            for (int k = 0; k < 9; ++k) {
                const int dh = k / 3 - 1, dw = k % 3 - 1;
                const int hh = h + dh, ww = w + dw;
                float v = ((unsigned)hh < 128u && (unsigned)ww < 128u)
                          ? xc[dh * WPX + dw] : 0.f;
                acc = fmaf(kg[k], v, acc);
            }
            outb[(size_t)c * HW] = acc;
        }
    }
}

extern "C" void kernel_launch(void* const* d_in, const int* in_sizes, int n_in,
                              void* d_out, int out_size, void* d_ws, size_t ws_size,
                              hipStream_t stream) {
    const float* x        = (const float*)d_in[0];
    const float* w_reduce = (const float*)d_in[1];
    const float* b_reduce = (const float*)d_in[2];
    const float* w_span   = (const float*)d_in[3];
    const float* b_span   = (const float*)d_in[4];
    float* out = (float*)d_out;

    const size_t ws_needed = (size_t)(72 + 4 * 64 * 18) * sizeof(float);  // 18720 B
    if (ws_size >= ws_needed) {
        float* ws = (float*)d_ws;
        invol_setup<<<18, 256, 0, stream>>>(w_reduce, b_reduce, w_span, b_span, ws);
        const int npix = 8 * 128 * 128;               // 131072
        invol_main<<<npix / 256 * 4, 256, 0, stream>>>(x, ws, out);
    } else {
        const int npix = 8 * 128 * 128;
        invol_fused_fallback<<<npix / 256, 256, 0, stream>>>(
            x, w_reduce, b_reduce, w_span, b_span, out);
    }
}

// Round 4
// 46.067 us; speedup vs baseline: 10.7797x; 1.0150x over previous
//
#include <hip/hip_runtime.h>

// Involution b=8, c=64, h=w=128, K=3, G=8, r=2.
// kern = Wc @ x_center + bb, Wc = w_span@w_reduce (72x64), bb = w_span@b_reduce + b_span.
// R11: 2 pixels/thread + OCTANT split (1 group = 8 channels per block).
//   - Fixes R8's failure mode: kg = 9 x float2 (18 VGPR, same as R7), Phase-A
//     cluster body identical size to R7 -> full unroll, no scratch.
//   - Grid stays 2048 blocks (256 pair-blocks x 8 octants) -> full residency.
//   - Per-wave serialized memory ops: PhA 64 float2 loads serve 2 px;
//     PhB 72 loads (was 144); SGPR weight traffic per cluster halved.
//   - XCD swizzle: XCD k -> pair-blocks k*32..k*32+31 = exactly image k (4MiB=L2).
// R9/R10 post-mortem: time invariant to VALU count and to DS-vs-vmem pipe ->
//   latency-exposure bound; attack per-wave round-trips, keep compiler free.

#define HW 16384   // 128*128
#define WPX 128

// ws layout: [0,72) bb ;  [72 + o*576 + c*9 + j) Wg[o][c][j]   (o=group 0..7)
__global__ void invol_setup(const float* __restrict__ w_reduce,
                            const float* __restrict__ b_reduce,
                            const float* __restrict__ w_span,
                            const float* __restrict__ b_span,
                            float* __restrict__ ws)
{
    const int tid = blockIdx.x * 256 + threadIdx.x;   // 0..4607
    if (tid >= 72 * 64) return;
    const int row = tid >> 6;     // 0..71  (= g*9 + j)
    const int c   = tid & 63;
    float s = 0.f;
#pragma unroll
    for (int i = 0; i < 32; ++i)
        s = fmaf(w_span[row * 32 + i], w_reduce[i * 64 + c], s);
    ws[72 + (row / 9) * 576 + c * 9 + (row % 9)] = s;
    if (c == 0) {
        float t = b_span[row];
#pragma unroll
        for (int i = 0; i < 32; ++i)
            t = fmaf(w_span[row * 32 + i], b_reduce[i], t);
        ws[row] = t;
    }
}

__global__ __launch_bounds__(256, 4) void invol_main(
    const float* __restrict__ x,
    const float* __restrict__ ws,
    float* __restrict__ out)
{
    // XCD-aware swizzle: nwg = 2048, 8 XCDs, 256 logical ids per XCD.
    const int bid     = blockIdx.x;
    const int logical = (bid & 7) * 256 + (bid >> 3);
    const int o  = logical & 7;             // octant / group — SCALAR (SGPR)
    const int pb = logical >> 3;            // pair-block (256 pixel-pairs)

    const int P2  = pb * 256 + threadIdx.x; // pixel-pair id, 0..65535
    const int b   = P2 >> 13;               // 8192 pairs per image
    const int hw0 = (P2 & 8191) << 1;       // even pixel index
    const int h   = hw0 >> 7;
    const int w0  = hw0 & 127;              // even, 0..126

    const size_t imgoff = (size_t)b * 64 * HW;
    const float* xb  = x + imgoff + hw0;
    const float* Wg  = ws + 72 + o * 576;   // [c][9], scalar base
    const float* bbg = ws + o * 9;          // group bias, 9 floats

    // ---- phase A: 8-wide float2 clusters, 9 paired accumulators ----
    float2 kg[9];
#pragma unroll
    for (int j = 0; j < 9; ++j) { const float t = bbg[j]; kg[j] = make_float2(t, t); }

#pragma unroll
    for (int c0 = 0; c0 < 64; c0 += 8) {
        float2 xv[8];
#pragma unroll
        for (int i = 0; i < 8; ++i)
            xv[i] = *reinterpret_cast<const float2*>(xb + (size_t)(c0 + i) * HW);
#pragma unroll
        for (int i = 0; i < 8; ++i) {
#pragma unroll
            for (int j = 0; j < 9; ++j) {
                const float wv = Wg[(c0 + i) * 9 + j];
                kg[j].x = fmaf(wv, xv[i].x, kg[j].x);
                kg[j].y = fmaf(wv, xv[i].y, kg[j].y);
            }
        }
    }

    // ---- phase B prep: row-clamped offsets, masks folded into taps ----
    int rof[3];
#pragma unroll
    for (int t = 0; t < 3; ++t) {
        const int hh = h + t - 1;
        const int hc = hh < 0 ? 0 : (hh > 127 ? 127 : hh);
        rof[t] = (hc - h) * WPX;
        const float m = ((unsigned)hh < 128u) ? 1.f : 0.f;
#pragma unroll
        for (int d = 0; d < 3; ++d) { kg[t * 3 + d].x *= m; kg[t * 3 + d].y *= m; }
    }
    // column edges: px0 (w=w0) loses left taps only at w0==0; px1 (w=w0+1)
    // loses right taps only at w0==126. Edge loads are clamped in-bounds;
    // the clamped (finite) value is multiplied by a zeroed tap.
    const int dwl = (w0 == 0)   ? 0 : -1;   // col of left scalar load rel. w0
    const int dwr = (w0 == 126) ? 1 : 2;    // col of right scalar load rel. w0
    if (w0 == 0)   { kg[0].x = 0.f; kg[3].x = 0.f; kg[6].x = 0.f; }
    if (w0 == 126) { kg[2].y = 0.f; kg[5].y = 0.f; kg[8].y = 0.f; }

    // ---- phase B: 8 channels; 3x{float2 + 2 scalar} loads, 18 FMA, f2 store ----
#pragma unroll
    for (int ci = 0; ci < 8; ++ci) {
        const int c = o * 8 + ci;
        const float* xc = xb + (size_t)c * HW;
        float2 vC[3];
        float  vL[3], vR[3];
#pragma unroll
        for (int t = 0; t < 3; ++t) {
            vC[t] = *reinterpret_cast<const float2*>(xc + rof[t]); // cols w0,w0+1
            vL[t] = xc[rof[t] + dwl];                              // col w0-1 (clamped)
            vR[t] = xc[rof[t] + dwr];                              // col w0+2 (clamped)
        }
        float acc0 = 0.f, acc1 = 0.f;
#pragma unroll
        for (int t = 0; t < 3; ++t) {
            acc0 = fmaf(kg[t * 3 + 0].x, vL[t],   acc0);
            acc0 = fmaf(kg[t * 3 + 1].x, vC[t].x, acc0);
            acc0 = fmaf(kg[t * 3 + 2].x, vC[t].y, acc0);
            acc1 = fmaf(kg[t * 3 + 0].y, vC[t].x, acc1);
            acc1 = fmaf(kg[t * 3 + 1].y, vC[t].y, acc1);
            acc1 = fmaf(kg[t * 3 + 2].y, vR[t],   acc1);
        }
        *reinterpret_cast<float2*>(out + imgoff + (size_t)c * HW + hw0) =
            make_float2(acc0, acc1);
    }
}

// fallback (round-1 kernel) if ws is too small for the weight scratch
__global__ __launch_bounds__(256) void invol_fused_fallback(
    const float* __restrict__ x,
    const float* __restrict__ w_reduce,
    const float* __restrict__ b_reduce,
    const float* __restrict__ w_span,
    const float* __restrict__ b_span,
    float* __restrict__ out)
{
    const int pid = blockIdx.x * 256 + threadIdx.x;
    const int b  = pid >> 14;
    const int hw = pid & 16383;
    const int h  = hw >> 7;
    const int w  = hw & 127;
    const float* xb   = x   + (size_t)b * 64 * HW + hw;
    float*       outb = out + (size_t)b * 64 * HW + hw;
    float y[32];
#pragma unroll
    for (int o = 0; o < 32; ++o) y[o] = b_reduce[o];
#pragma unroll 4
    for (int c = 0; c < 64; ++c) {
        const float xc = xb[(size_t)c * HW];
#pragma unroll
        for (int o = 0; o < 32; ++o)
            y[o] = fmaf(w_reduce[o * 64 + c], xc, y[o]);
    }
    for (int g = 0; g < 8; ++g) {
        float kg[9];
#pragma unroll
        for (int k = 0; k < 9; ++k) {
            float s = b_span[g * 9 + k];
#pragma unroll
            for (int i = 0; i < 32; ++i)
                s = fmaf(w_span[(g * 9 + k) * 32 + i], y[i], s);
            kg[k] = s;
        }
#pragma unroll
        for (int ci = 0; ci < 8; ++ci) {
            const int c = g * 8 + ci;
            const float* xc = xb + (size_t)c * HW;
            float acc = 0.f;
#pragma unroll
            for (int k = 0; k < 9; ++k) {
                const int dh = k / 3 - 1, dw = k % 3 - 1;
                const int hh = h + dh, ww = w + dw;
                float v = ((unsigned)hh < 128u && (unsigned)ww < 128u)
                          ? xc[dh * WPX + dw] : 0.f;
                acc = fmaf(kg[k], v, acc);
            }
            outb[(size_t)c * HW] = acc;
        }
    }
}

extern "C" void kernel_launch(void* const* d_in, const int* in_sizes, int n_in,
                              void* d_out, int out_size, void* d_ws, size_t ws_size,
                              hipStream_t stream) {
    const float* x        = (const float*)d_in[0];
    const float* w_reduce = (const float*)d_in[1];
    const float* b_reduce = (const float*)d_in[2];
    const float* w_span   = (const float*)d_in[3];
    const float* b_span   = (const float*)d_in[4];
    float* out = (float*)d_out;

    const size_t ws_needed = (size_t)(72 + 8 * 64 * 9) * sizeof(float);  // 18720 B
    if (ws_size >= ws_needed) {
        float* ws = (float*)d_ws;
        invol_setup<<<18, 256, 0, stream>>>(w_reduce, b_reduce, w_span, b_span, ws);
        const int npairs = 8 * 128 * 128 / 2;          // 65536
        invol_main<<<npairs / 256 * 8, 256, 0, stream>>>(x, ws, out);  // 2048 blocks
    } else {
        const int npix = 8 * 128 * 128;
        invol_fused_fallback<<<npix / 256, 256, 0, stream>>>(
            x, w_reduce, b_reduce, w_span, b_span, out);
    }
}